// Round 3
// baseline (1391.575 us; speedup 1.0000x reference)
//
#include <hip/hip_runtime.h>
#include <stdint.h>

// ---------------------------------------------------------------------------
// TContrastive: GRACE InfoNCE loss.
//   loss_view = (1/2N) sum_i log(S_i - e^2) - (2/N) sum_i g12_i
// where S = row sums of exp(2 * M M^T), M = [n1; n2] row-normalized (16384x1024).
// R1: Gram symmetry — triangle tiles only, row+col exp sums.
// R2: Gram in MX-fp8 (mfma_scale 16x16x128, uniform scale=1.0) — rows are
//     unit-norm so fixed scale loses nothing; 2x MFMA rate vs bf16.
// Projections stay bf16 MFMA (16x16x32), fp32 accumulate. tau = 0.5.
// ---------------------------------------------------------------------------

typedef unsigned short u16;
typedef __attribute__((ext_vector_type(8))) __bf16 bf16x8;
typedef __attribute__((ext_vector_type(4))) float f32x4;
typedef __attribute__((ext_vector_type(8))) int i32x8;

#define NS 8192       // samples per view half
#define DD 1024       // feature dim

__device__ __forceinline__ float bf2f(u16 u) {
    union { uint32_t i; float f; } v; v.i = ((uint32_t)u) << 16; return v.f;
}
__device__ __forceinline__ u16 f2bf(float f) {
    union { float f; uint32_t i; } v; v.f = f;
    return (u16)((v.i + 0x7FFFu + ((v.i >> 16) & 1u)) >> 16);   // RNE
}

// async global->LDS, 16B per lane. LDS dest must be wave-uniform base + lane*16.
__device__ __forceinline__ void gload16(const void* g, void* l) {
    __builtin_amdgcn_global_load_lds(
        (__attribute__((address_space(1))) void*)(uintptr_t)(g),
        (__attribute__((address_space(3))) void*)(uintptr_t)(l), 16, 0, 0);
}

// ---------------- elementwise conversion kernels ----------------

__global__ __launch_bounds__(256) void conv_f2bf(const float* __restrict__ src,
                                                 u16* __restrict__ dst) {
    int i = (blockIdx.x * 256 + threadIdx.x) * 4;
    float4 v = *(const float4*)(src + i);
    ushort4 o;
    o.x = f2bf(v.x); o.y = f2bf(v.y); o.z = f2bf(v.z); o.w = f2bf(v.w);
    *(ushort4*)(dst + i) = o;
}

// Z = bf16([ta; tb]) row view (16384x1024), 16384 blocks
__global__ __launch_bounds__(256) void conv_cat(const float* __restrict__ a,
                                                const float* __restrict__ b,
                                                u16* __restrict__ Z) {
    size_t i = (size_t)(blockIdx.x * 256 + threadIdx.x) * 4;
    const size_t half = (size_t)NS * DD;
    const float* s = (i < half) ? (a + i) : (b + (i - half));
    float4 v = *(const float4*)s;
    ushort4 o;
    o.x = f2bf(v.x); o.y = f2bf(v.y); o.z = f2bf(v.z); o.w = f2bf(v.w);
    *(ushort4*)(Z + i) = o;
}

// column view: Z[i, b*32+a] = src[i, a*32+b]  (per-row 32x32 transpose)
__global__ __launch_bounds__(256) void conv_col(const float* __restrict__ a,
                                                const float* __restrict__ b,
                                                u16* __restrict__ Z) {
    size_t i = (size_t)(blockIdx.x * 256 + threadIdx.x) * 4;
    const size_t half = (size_t)NS * DD;
    const float* src; size_t o;
    if (i < half) { src = a; o = i; } else { src = b; o = i - half; }
    size_t row = o >> 10;
    int j = (int)(o & 1023);
    int aI = j & 31, bI = j >> 5;      // j = b*32 + a
    const float* rp = src + (row << 10);
    ushort4 ov;
    ov.x = f2bf(rp[aI * 32 + bI]);
    ov.y = f2bf(rp[(aI + 1) * 32 + bI]);
    ov.z = f2bf(rp[(aI + 2) * 32 + bI]);
    ov.w = f2bf(rp[(aI + 3) * 32 + bI]);
    *(ushort4*)(Z + i) = ov;
}

// ---------------- bf16 GEMM: C[m,n] = sum_k A[m,k] * B[n,k]
// MODE 0: out = bf16(elu(C + bias))      (fc_a)
// MODE 1: out = bf16(C + bias)           (fc_b)
template <int MODE>
__global__ __launch_bounds__(256) void gemm_bt(const u16* A, const u16* B,
                                               const float* __restrict__ bias,
                                               u16* __restrict__ out) {
    __shared__ alignas(16) u16 As[128 * 32];
    __shared__ alignas(16) u16 Bs[128 * 32];
    const int tid = threadIdx.x;

    const int tm = blockIdx.y, tn = blockIdx.x;
    const size_t tileM = (size_t)tm * 128;
    const size_t tileN = (size_t)tn * 128;

    const u16* gA0 = A + (tileM + (tid >> 2)) * DD + (tid & 3) * 8;
    const u16* gA1 = gA0 + (size_t)64 * DD;
    const u16* gB0 = B + (tileN + (tid >> 2)) * DD + (tid & 3) * 8;
    const u16* gB1 = gB0 + (size_t)64 * DD;
    u16* lA0 = &As[tid * 8]; u16* lA1 = lA0 + 2048;
    u16* lB0 = &Bs[tid * 8]; u16* lB1 = lB0 + 2048;

    const int lane = tid & 63;
    const int wv = tid >> 6;
    const int wr = (wv >> 1) << 6;
    const int wc = (wv & 1) << 6;
    const int lr = lane & 15;
    const int lh = lane >> 4;

    const u16* aBase = &As[(wr + lr) * 32 + lh * 8];
    const u16* bBase = &Bs[(wc + lr) * 32 + lh * 8];

    f32x4 acc[4][4];
#pragma unroll
    for (int i = 0; i < 4; i++)
#pragma unroll
        for (int j = 0; j < 4; j++) acc[i][j] = (f32x4)0.0f;

    for (int k0 = 0; k0 < DD; k0 += 32) {
        gload16(gA0 + k0, lA0);
        gload16(gA1 + k0, lA1);
        gload16(gB0 + k0, lB0);
        gload16(gB1 + k0, lB1);
        __syncthreads();
        bf16x8 af[4], bfr[4];
#pragma unroll
        for (int rt = 0; rt < 4; rt++) af[rt] = *(const bf16x8*)(aBase + rt * 512);
#pragma unroll
        for (int ct = 0; ct < 4; ct++) bfr[ct] = *(const bf16x8*)(bBase + ct * 512);
#pragma unroll
        for (int rt = 0; rt < 4; rt++)
#pragma unroll
            for (int ct = 0; ct < 4; ct++)
                acc[rt][ct] = __builtin_amdgcn_mfma_f32_16x16x32_bf16(
                    af[rt], bfr[ct], acc[rt][ct], 0, 0, 0);
        __syncthreads();
    }

    float bcol[4];
#pragma unroll
    for (int ct = 0; ct < 4; ct++) bcol[ct] = bias[tileN + wc + ct * 16 + lr];
#pragma unroll
    for (int rt = 0; rt < 4; rt++) {
#pragma unroll
        for (int r = 0; r < 4; r++) {
            size_t row = tileM + wr + rt * 16 + lh * 4 + r;
            u16* orow = out + row * DD + tileN + wc + lr;
#pragma unroll
            for (int ct = 0; ct < 4; ct++) {
                float v = acc[rt][ct][r] + bcol[ct];
                if (MODE == 0) v = v > 0.0f ? v : expm1f(v);
                orow[ct * 16] = f2bf(v);
            }
        }
    }
}

// ---------------- MX-fp8 triangular Gram ----------------
// S[row] += sum_col exp(2*G), off-diag tiles also S[col] += exp-col-sums.
// M is fp8(e4m3) row-normalized, row stride DD bytes. Grid dim3(129, 64).
// LDS 16B granules XOR-swizzled: phys granule g = r*8 + (c ^ (r&7)),
// implemented by permuting the global SOURCE addresses (dest stays lane*16).
__global__ __launch_bounds__(256) void gram_fp8(const uint8_t* __restrict__ M,
                                                float* __restrict__ S) {
    __shared__ alignas(16) uint8_t As[128 * 128];
    __shared__ alignas(16) uint8_t Bs[128 * 128];
    const int tid = threadIdx.x;

    // triangle decode: covers each (i<=j) tile pair exactly once
    int x = blockIdx.x, y = blockIdx.y;          // x in [0,129), y in [0,64)
    int tm, tn;
    if (y + x < 128) { tm = y;       tn = y + x; }
    else             { tm = 127 - y; tn = x - 1; }
    const size_t tileM = (size_t)tm * 128;
    const size_t tileN = (size_t)tn * 128;

    // staging: round i, thread t writes phys granule 256*i + t;
    // inverse of swizzle: r = g>>3 = 32*i + (t>>3), c = (t&7) ^ (r&7) — i-invariant.
    const int r0 = tid >> 3;                     // [0,32)
    const int c0 = (tid & 7) ^ (r0 & 7);
    const uint8_t* gA = M + (tileM + r0) * DD + c0 * 16;
    const uint8_t* gB = M + (tileN + r0) * DD + c0 * 16;
    uint8_t* lA = As + tid * 16;
    uint8_t* lB = Bs + tid * 16;

    const int lane = tid & 63;
    const int wv = tid >> 6;
    const int wr = (wv >> 1) << 6;
    const int wc = (wv & 1) << 6;
    const int lr = lane & 15;                    // m/n index; C: col
    const int lh = lane >> 4;                    // k-group; C: row-group
    // lane's 32 K-bytes = logical chunks 2*lh, 2*lh+1; row&7 == lr&7 for all tiles
    const int e0 = ((2 * lh) ^ (lr & 7)) * 16;
    const int e1 = ((2 * lh + 1) ^ (lr & 7)) * 16;

    f32x4 acc[4][4];
#pragma unroll
    for (int i = 0; i < 4; i++)
#pragma unroll
        for (int j = 0; j < 4; j++) acc[i][j] = (f32x4)0.0f;

    for (int k0 = 0; k0 < DD; k0 += 128) {
#pragma unroll
        for (int i = 0; i < 4; i++)
            gload16(gA + (size_t)i * 32 * DD + k0, lA + i * 4096);
#pragma unroll
        for (int i = 0; i < 4; i++)
            gload16(gB + (size_t)i * 32 * DD + k0, lB + i * 4096);
        __syncthreads();

        i32x8 bfr[4];
#pragma unroll
        for (int ct = 0; ct < 4; ct++) {
            const uint8_t* bp = Bs + (wc + ct * 16 + lr) * 128;
            uint4 lo = *(const uint4*)(bp + e0);
            uint4 hi = *(const uint4*)(bp + e1);
            bfr[ct] = (i32x8){(int)lo.x, (int)lo.y, (int)lo.z, (int)lo.w,
                              (int)hi.x, (int)hi.y, (int)hi.z, (int)hi.w};
        }
#pragma unroll
        for (int rt = 0; rt < 4; rt++) {
            const uint8_t* ap = As + (wr + rt * 16 + lr) * 128;
            uint4 lo = *(const uint4*)(ap + e0);
            uint4 hi = *(const uint4*)(ap + e1);
            i32x8 af = {(int)lo.x, (int)lo.y, (int)lo.z, (int)lo.w,
                        (int)hi.x, (int)hi.y, (int)hi.z, (int)hi.w};
#pragma unroll
            for (int ct = 0; ct < 4; ct++)
                acc[rt][ct] = __builtin_amdgcn_mfma_scale_f32_16x16x128_f8f6f4(
                    af, bfr[ct], acc[rt][ct],
                    0, 0,                       // cbsz=fp8, blgp=fp8
                    0, 0x7F7F7F7F,              // A: opsel, scale bytes = 127 (1.0)
                    0, 0x7F7F7F7F);             // B: opsel, scale
        }
        __syncthreads();
    }

    const bool offdiag = (tm != tn);
    float colsum[4] = {0.f, 0.f, 0.f, 0.f};
#pragma unroll
    for (int rt = 0; rt < 4; rt++) {
#pragma unroll
        for (int r = 0; r < 4; r++) {
            float rs = 0.0f;
#pragma unroll
            for (int ct = 0; ct < 4; ct++) {
                float e = __expf(2.0f * acc[rt][ct][r]);
                rs += e;
                colsum[ct] += e;
            }
            rs += __shfl_xor(rs, 1);
            rs += __shfl_xor(rs, 2);
            rs += __shfl_xor(rs, 4);
            rs += __shfl_xor(rs, 8);
            if (lr == 0) {
                size_t row = tileM + wr + rt * 16 + lh * 4 + r;
                atomicAdd(&S[row], rs);
            }
        }
    }
    if (offdiag) {
#pragma unroll
        for (int ct = 0; ct < 4; ct++) {
            float cs = colsum[ct];
            cs += __shfl_xor(cs, 16);
            cs += __shfl_xor(cs, 32);
            if (lh == 0) {
                size_t col = tileN + wc + ct * 16 + lr;
                atomicAdd(&S[col], cs);
            }
        }
    }
}

// row-normalize bf16 matrix in place; also emit fp8(e4m3) copy for the Gram
__global__ __launch_bounds__(256) void normalize_kernel(u16* M, uint8_t* F) {
    __shared__ float red[4];
    const int tid = threadIdx.x;
    u16* row = M + ((size_t)blockIdx.x << 10);
    ushort4 v = ((const ushort4*)row)[tid];
    float x0 = bf2f(v.x), x1 = bf2f(v.y), x2 = bf2f(v.z), x3 = bf2f(v.w);
    float s = x0 * x0 + x1 * x1 + x2 * x2 + x3 * x3;
#pragma unroll
    for (int m = 1; m < 64; m <<= 1) s += __shfl_xor(s, m);
    if ((tid & 63) == 0) red[tid >> 6] = s;
    __syncthreads();
    float inv = rsqrtf(red[0] + red[1] + red[2] + red[3]);
    float y0 = x0 * inv, y1 = x1 * inv, y2 = x2 * inv, y3 = x3 * inv;
    ushort4 o;
    o.x = f2bf(y0); o.y = f2bf(y1); o.z = f2bf(y2); o.w = f2bf(y3);
    ((ushort4*)row)[tid] = o;
    int pk = __builtin_amdgcn_cvt_pk_fp8_f32(y0, y1, 0, false);
    pk = __builtin_amdgcn_cvt_pk_fp8_f32(y2, y3, pk, true);
    ((int*)(F + ((size_t)blockIdx.x << 10)))[tid] = pk;
}

// g12[i] = dot(M[i], M[i+NS])  (one block per i)
__global__ __launch_bounds__(256) void diag_kernel(const u16* M, float* g12) {
    __shared__ float red[4];
    const int tid = threadIdx.x;
    const u16* r1 = M + ((size_t)blockIdx.x << 10);
    const u16* r2 = r1 + ((size_t)NS << 10);
    ushort4 a = ((const ushort4*)r1)[tid];
    ushort4 b = ((const ushort4*)r2)[tid];
    float s = bf2f(a.x) * bf2f(b.x) + bf2f(a.y) * bf2f(b.y) +
              bf2f(a.z) * bf2f(b.z) + bf2f(a.w) * bf2f(b.w);
#pragma unroll
    for (int m = 1; m < 64; m <<= 1) s += __shfl_xor(s, m);
    if ((tid & 63) == 0) red[tid >> 6] = s;
    __syncthreads();
    if (tid == 0) g12[blockIdx.x] = red[0] + red[1] + red[2] + red[3];
}

__global__ __launch_bounds__(256) void final_kernel(const float* Sr, const float* Sc,
                                                    const float* gr, const float* gc,
                                                    const float* w_r1, float* out) {
    __shared__ float red[16];
    const float E2 = 7.389056098930650f;  // exp(1/tau), tau=0.5
    float a = 0.f, b = 0.f, c = 0.f, d = 0.f;
    for (int i = threadIdx.x; i < 2 * NS; i += 256) {
        a += logf(Sr[i] - E2);
        b += logf(Sc[i] - E2);
    }
    for (int i = threadIdx.x; i < NS; i += 256) {
        c += gr[i];
        d += gc[i];
    }
#pragma unroll
    for (int m = 1; m < 64; m <<= 1) {
        a += __shfl_xor(a, m); b += __shfl_xor(b, m);
        c += __shfl_xor(c, m); d += __shfl_xor(d, m);
    }
    int w = threadIdx.x >> 6;
    if ((threadIdx.x & 63) == 0) {
        red[w] = a; red[4 + w] = b; red[8 + w] = c; red[12 + w] = d;
    }
    __syncthreads();
    if (threadIdx.x == 0) {
        a = red[0] + red[1] + red[2] + red[3];
        b = red[4] + red[5] + red[6] + red[7];
        c = red[8] + red[9] + red[10] + red[11];
        d = red[12] + red[13] + red[14] + red[15];
        float lr = a / (2.0f * NS) - 2.0f * c / NS;
        float lc = b / (2.0f * NS) - 2.0f * d / NS;
        float w0 = w_r1[0];
        w0 = fminf(fmaxf(w0, 0.0f), 1.0f);
        out[0] = w0 * lr + (1.0f - w0) * lc;
    }
}

extern "C" void kernel_launch(void* const* d_in, const int* in_sizes, int n_in,
                              void* d_out, int out_size, void* d_ws, size_t ws_size,
                              hipStream_t stream) {
    const float* ta = (const float*)d_in[0];
    const float* tb = (const float*)d_in[1];
    const float* W1 = (const float*)d_in[2];
    const float* b1 = (const float*)d_in[3];
    const float* W2 = (const float*)d_in[4];
    const float* b2 = (const float*)d_in[5];
    const float* W3 = (const float*)d_in[6];
    const float* b3 = (const float*)d_in[7];
    const float* W4 = (const float*)d_in[8];
    const float* b4 = (const float*)d_in[9];
    const float* wr = (const float*)d_in[10];
    float* out = (float*)d_out;

    char* p = (char*)d_ws;
    const size_t MAT = (size_t)2 * NS * DD * sizeof(u16);  // 33.5 MB
    u16* Z = (u16*)p;  p += MAT;
    u16* T = (u16*)p;  p += MAT;      // also reused as the fp8 Gram input
    u16* H = (u16*)p;  p += MAT;
    u16* Wb = (u16*)p; p += (size_t)4 * DD * DD * sizeof(u16);
    float* Sr = (float*)p;  p += 2 * NS * sizeof(float);
    float* Sc = (float*)p;  p += 2 * NS * sizeof(float);
    float* gr = (float*)p;  p += NS * sizeof(float);
    float* gc = (float*)p;  p += NS * sizeof(float);

    u16* Wb1 = Wb;
    u16* Wb2 = Wb + (size_t)DD * DD;
    u16* Wb3 = Wb + (size_t)2 * DD * DD;
    u16* Wb4 = Wb + (size_t)3 * DD * DD;
    uint8_t* Hf8 = (uint8_t*)T;       // T is dead after gemm<1>; serial stream

    conv_f2bf<<<1024, 256, 0, stream>>>(W1, Wb1);
    conv_f2bf<<<1024, 256, 0, stream>>>(W2, Wb2);
    conv_f2bf<<<1024, 256, 0, stream>>>(W3, Wb3);
    conv_f2bf<<<1024, 256, 0, stream>>>(W4, Wb4);
    hipMemsetAsync(Sr, 0, 4 * NS * sizeof(float), stream);  // Sr and Sc contiguous

    // ---- row view ----
    conv_cat<<<16384, 256, 0, stream>>>(ta, tb, Z);
    gemm_bt<0><<<dim3(8, 128), 256, 0, stream>>>(Z, Wb1, b1, T);
    gemm_bt<1><<<dim3(8, 128), 256, 0, stream>>>(T, Wb2, b2, H);
    normalize_kernel<<<16384, 256, 0, stream>>>(H, Hf8);
    diag_kernel<<<8192, 256, 0, stream>>>(H, gr);
    gram_fp8<<<dim3(129, 64), 256, 0, stream>>>(Hf8, Sr);

    // ---- column view ----
    conv_col<<<16384, 256, 0, stream>>>(ta, tb, Z);
    gemm_bt<0><<<dim3(8, 128), 256, 0, stream>>>(Z, Wb3, b3, T);
    gemm_bt<1><<<dim3(8, 128), 256, 0, stream>>>(T, Wb4, b4, H);
    normalize_kernel<<<16384, 256, 0, stream>>>(H, Hf8);
    diag_kernel<<<8192, 256, 0, stream>>>(H, gc);
    gram_fp8<<<dim3(129, 64), 256, 0, stream>>>(Hf8, Sc);

    final_kernel<<<1, 256, 0, stream>>>(Sr, Sc, gr, gc, wr, out);
}